// Round 2
// baseline (164.027 us; speedup 1.0000x reference)
//
#include <hip/hip_runtime.h>
#include <hip/hip_bf16.h>
#include <stdint.h>

#define T_SEQ 2048
#define DH    128
#define BQ    64
#define BKV   64
#define QSCALE 0.12751742796f   // (1/sqrt(128)) * log2(e): exp2-domain softmax

typedef short  short8 __attribute__((ext_vector_type(8)));
typedef __bf16 bf16x8 __attribute__((ext_vector_type(8)));
typedef float  f32x4  __attribute__((ext_vector_type(4)));

__device__ __forceinline__ bf16x8 as_bf16x8(short8 x) { return __builtin_bit_cast(bf16x8, x); }

__device__ __forceinline__ uint32_t bf_bits(float x) {
  union { __hip_bfloat16 h; unsigned short u; } cv;
  cv.h = __float2bfloat16(x);
  return (uint32_t)cv.u;
}

// ---------------- pre-pass: fp32 -> bf16 ----------------
__global__ void convert_bf16(const float* __restrict__ src, unsigned short* __restrict__ dst,
                             int n4) {
  int i = blockIdx.x * 256 + threadIdx.x;
  if (i >= n4) return;
  const float4 f = ((const float4*)src)[i];
  union { unsigned short us[4]; uint2 u2; } o;
  o.us[0] = (unsigned short)bf_bits(f.x);
  o.us[1] = (unsigned short)bf_bits(f.y);
  o.us[2] = (unsigned short)bf_bits(f.z);
  o.us[3] = (unsigned short)bf_bits(f.w);
  ((uint2*)dst)[i] = o.u2;
}

// ---------------- pre-pass: V[n][t][d] -> Vt[n][d][t] bf16 ----------------
__global__ void transpose_v_bf16(const float* __restrict__ v, unsigned short* __restrict__ vt) {
  __shared__ float tile[32][33];
  const int n = blockIdx.z, d0 = blockIdx.y * 32, t0 = blockIdx.x * 32;
  const int tx = threadIdx.x, ty = threadIdx.y;  // (32, 8)
  #pragma unroll
  for (int i = 0; i < 32; i += 8)
    tile[ty + i][tx] = v[((size_t)n * T_SEQ + t0 + ty + i) * DH + d0 + tx];
  __syncthreads();
  #pragma unroll
  for (int i = 0; i < 32; i += 8)
    vt[((size_t)n * DH + d0 + ty + i) * T_SEQ + t0 + tx] = (unsigned short)bf_bits(tile[tx][ty + i]);
}

// ---------------- flash attention fwd (causal), bf16 MFMA ----------------
// Per block: 64 q-rows (wave w owns rows q0+16w..+15), KV tiles of 64.
// S^T = mfma(A=K_tile, B=Q): lane holds S for q = lane&15, kv = 16*ma + 4*(lane>>4) + reg.
// O^T = mfma(A=V^T_tile, B=P^T): lane holds O for q = lane&15, d = 16*dsub + 4*(lane>>4) + reg.
// Fragment layout (HW-verified, m97/m89): A/B lane l <-> [l&15][(l>>4)*8+j]; C/D col=l&15, row=(l>>4)*4+reg.
__global__ __launch_bounds__(256, 2) void attn_fwd(
    const float* __restrict__ Qf,
    const unsigned short* __restrict__ Kb,
    const unsigned short* __restrict__ Vt,
    float* __restrict__ Out,
    const int* __restrict__ maskp)
{
  __shared__ __align__(16) char smem[65536];  // K bufs: 2x16KB @0, V^T bufs: 2x16KB @32768

  const int tid  = threadIdx.x;
  const int lane = tid & 63;
  const int w    = tid >> 6;
  const int m15  = lane & 15;
  const int g    = lane >> 4;
  const int n    = blockIdx.y;

  // causal load-balance: XCD = (linear block id)%8 = bx%8; classes {r,15-r,16+r,31-r} sum to 62.
  const int bx = blockIdx.x;
  const int r8 = bx & 7, j8 = bx >> 3;
  const int qt = (j8 == 0) ? r8 : (j8 == 1) ? (15 - r8) : (j8 == 2) ? (16 + r8) : (31 - r8);
  const int q0 = qt * BQ;
  const int masked = maskp[0];
  const int nkt = masked ? (qt + 1) : (T_SEQ / BKV);

  const int qrow = q0 + 16 * w + m15;

  // Q B-fragments, converted fp32->bf16 in-kernel with scale*log2e folded:
  // lane needs Q[q=m15-row][k = 32*kf + 8*g + j], j=0..7.
  bf16x8 qf[4];
  {
    const float* qg = Qf + ((size_t)n * T_SEQ + qrow) * DH;
    #pragma unroll
    for (int kf = 0; kf < 4; ++kf) {
      const float4 f0 = *(const float4*)(qg + 32 * kf + 8 * g);
      const float4 f1 = *(const float4*)(qg + 32 * kf + 8 * g + 4);
      union { unsigned short us[8]; short8 s8; } qa;
      qa.us[0] = (unsigned short)bf_bits(f0.x * QSCALE);
      qa.us[1] = (unsigned short)bf_bits(f0.y * QSCALE);
      qa.us[2] = (unsigned short)bf_bits(f0.z * QSCALE);
      qa.us[3] = (unsigned short)bf_bits(f0.w * QSCALE);
      qa.us[4] = (unsigned short)bf_bits(f1.x * QSCALE);
      qa.us[5] = (unsigned short)bf_bits(f1.y * QSCALE);
      qa.us[6] = (unsigned short)bf_bits(f1.z * QSCALE);
      qa.us[7] = (unsigned short)bf_bits(f1.w * QSCALE);
      qf[kf] = as_bf16x8(qa.s8);
    }
  }

  f32x4 acc[8] = {};
  float m_run = -3.0e38f;
  float ssum  = 0.f;
  const int swz = (m15 & 7) << 4;  // XOR swizzle bits for LDS reads (row&7 == m15&7 for both K and V^T)

  short8 kreg[4], vreg[4];
  const short8* gK = (const short8*)(Kb + (size_t)n * T_SEQ * DH);
  const short8* gV = (const short8*)(Vt + (size_t)n * DH * T_SEQ);

  auto loadRegs = [&](int kt) {
    const int t0 = kt * BKV;
    #pragma unroll
    for (int i = 0; i < 4; ++i) {                 // K: row = kv 0..63, 16B chunk = m15
      int row = 16 * w + 4 * i + g;
      kreg[i] = gK[(size_t)(t0 + row) * (DH / 8) + m15];
    }
    #pragma unroll
    for (int i = 0; i < 4; ++i) {                 // V^T: row = d 0..127, chunk = lane&7
      int d = 32 * w + 8 * i + (lane >> 3);
      vreg[i] = gV[(size_t)d * (T_SEQ / 8) + (t0 / 8) + (lane & 7)];
    }
  };
  auto writeRegs = [&](int buf) {                 // swizzled ds_write_b128
    #pragma unroll
    for (int i = 0; i < 4; ++i) {
      int row = 16 * w + 4 * i + g;
      int off = buf * 16384 + row * 256 + ((m15 * 16) ^ ((row & 7) << 4));
      *(short8*)(smem + off) = kreg[i];
    }
    #pragma unroll
    for (int i = 0; i < 4; ++i) {
      int d = 32 * w + 8 * i + (lane >> 3);
      int off = 32768 + buf * 16384 + d * 128 + (((lane & 7) * 16) ^ ((d & 7) << 4));
      *(short8*)(smem + off) = vreg[i];
    }
  };

  loadRegs(0);
  writeRegs(0);

  for (int kt = 0; kt < nkt; ++kt) {
    __syncthreads();                              // tile kt visible; all reads of buf (kt+1)&1 finished
    if (kt + 1 < nkt) loadRegs(kt + 1);           // issue next-tile global loads early (T14-lite)

    const char* kb = smem + (kt & 1) * 16384;
    const char* vb = smem + 32768 + (kt & 1) * 16384;

    // ---- S^T[64 kv][16 q] = K_tile * Q^T ----
    f32x4 s[4] = {};
    #pragma unroll
    for (int kf = 0; kf < 4; ++kf) {
      #pragma unroll
      for (int ma = 0; ma < 4; ++ma) {
        short8 kfr = *(const short8*)(kb + (16 * ma + m15) * 256 + ((g * 16 + 64 * kf) ^ swz));
        s[ma] = __builtin_amdgcn_mfma_f32_16x16x32_bf16(as_bf16x8(kfr), qf[kf], s[ma], 0, 0, 0);
      }
    }

    if (masked && kt == qt) {                     // diagonal tile: causal mask
      #pragma unroll
      for (int ma = 0; ma < 4; ++ma)
        #pragma unroll
        for (int rr = 0; rr < 4; ++rr) {
          int kvg = kt * BKV + ma * 16 + g * 4 + rr;
          if (kvg > qrow) s[ma][rr] = -1.0e30f;
        }
    }

    // ---- online softmax (exp2 domain); row q = m15 lives on lanes {q, q+16, q+32, q+48} ----
    float mx = s[0][0];
    #pragma unroll
    for (int ma = 0; ma < 4; ++ma)
      #pragma unroll
      for (int rr = 0; rr < 4; ++rr) mx = fmaxf(mx, s[ma][rr]);
    mx = fmaxf(mx, __shfl_xor(mx, 16));
    mx = fmaxf(mx, __shfl_xor(mx, 32));
    float mnew = fmaxf(m_run, mx);
    float corr = exp2f(m_run - mnew);

    float p[4][4];
    float lsum = 0.f;
    #pragma unroll
    for (int ma = 0; ma < 4; ++ma)
      #pragma unroll
      for (int rr = 0; rr < 4; ++rr) { p[ma][rr] = exp2f(s[ma][rr] - mnew); lsum += p[ma][rr]; }
    lsum += __shfl_xor(lsum, 16);
    lsum += __shfl_xor(lsum, 32);
    ssum = ssum * corr + lsum;
    m_run = mnew;
    #pragma unroll
    for (int i = 0; i < 8; ++i) {
      acc[i][0] *= corr; acc[i][1] *= corr; acc[i][2] *= corr; acc[i][3] *= corr;
    }

    // ---- pack P^T to bf16 pairs: u[ma][wd] = (p[ma][2wd], p[ma][2wd+1]) ----
    uint32_t u[4][2];
    #pragma unroll
    for (int ma = 0; ma < 4; ++ma) {
      u[ma][0] = bf_bits(p[ma][0]) | (bf_bits(p[ma][1]) << 16);
      u[ma][1] = bf_bits(p[ma][2]) | (bf_bits(p[ma][3]) << 16);
    }

    // ---- redistribute to B-frag layout: lane needs P^T[kv=32ks+8g+j][q=m15] ----
    // holder(kv): lane ((kv&15)>>2)*16 + q, value u[kv>>4][(kv&3)>>1]. For fixed (ks,g):
    // ma' = 2ks + (g>>1); j=0..3 from srcA = ((g&1)<<5)+q, j=4..7 from srcA+16.
    // (checked: lane17 ks0 needs kv8..15 -> lanes 33/49, u[0]; lane40 ks1 needs kv48..55 -> lanes 8/24, u[3])
    const int srcA = ((g & 1) << 5) + m15;
    const int sel  = g >> 1;
    bf16x8 pfr[2];
    #pragma unroll
    for (int ks = 0; ks < 2; ++ks) {
      uint32_t a00 = (uint32_t)__shfl((int)u[2 * ks + 0][0], srcA);
      uint32_t a01 = (uint32_t)__shfl((int)u[2 * ks + 0][1], srcA);
      uint32_t a10 = (uint32_t)__shfl((int)u[2 * ks + 1][0], srcA);
      uint32_t a11 = (uint32_t)__shfl((int)u[2 * ks + 1][1], srcA);
      uint32_t b00 = (uint32_t)__shfl((int)u[2 * ks + 0][0], srcA + 16);
      uint32_t b01 = (uint32_t)__shfl((int)u[2 * ks + 0][1], srcA + 16);
      uint32_t b10 = (uint32_t)__shfl((int)u[2 * ks + 1][0], srcA + 16);
      uint32_t b11 = (uint32_t)__shfl((int)u[2 * ks + 1][1], srcA + 16);
      union { uint32_t q[4]; short8 s8; } pu;
      pu.q[0] = sel ? a10 : a00;
      pu.q[1] = sel ? a11 : a01;
      pu.q[2] = sel ? b10 : b00;
      pu.q[3] = sel ? b11 : b01;
      pfr[ks] = as_bf16x8(pu.s8);
    }

    // ---- O^T[128 d][16 q] += V^T_tile * P^T ----
    #pragma unroll
    for (int dsub = 0; dsub < 8; ++dsub) {
      #pragma unroll
      for (int ks = 0; ks < 2; ++ks) {
        short8 vfr = *(const short8*)(vb + (16 * dsub + m15) * 128 + ((g * 16 + 64 * ks) ^ swz));
        acc[dsub] = __builtin_amdgcn_mfma_f32_16x16x32_bf16(as_bf16x8(vfr), pfr[ks], acc[dsub], 0, 0, 0);
      }
    }

    if (kt + 1 < nkt) writeRegs((kt + 1) & 1);    // ds_write after compute (load latency hidden)
  }

  const float inv = 1.0f / ssum;
  float* ob = Out + ((size_t)n * T_SEQ + qrow) * DH;
  #pragma unroll
  for (int dsub = 0; dsub < 8; ++dsub) {
    f32x4 o;
    o[0] = acc[dsub][0] * inv; o[1] = acc[dsub][1] * inv;
    o[2] = acc[dsub][2] * inv; o[3] = acc[dsub][3] * inv;
    *(f32x4*)(ob + dsub * 16 + g * 4) = o;
  }
}

extern "C" void kernel_launch(void* const* d_in, const int* in_sizes, int n_in,
                              void* d_out, int out_size, void* d_ws, size_t ws_size,
                              hipStream_t stream) {
  (void)in_sizes; (void)n_in; (void)out_size; (void)ws_size;
  const float* q = (const float*)d_in[0];
  const float* k = (const float*)d_in[1];
  const float* v = (const float*)d_in[2];
  const int* maskp = (const int*)d_in[3];
  float* out = (float*)d_out;

  const size_t elems = (size_t)16 * T_SEQ * DH;   // 4,194,304 per tensor
  unsigned short* Kb = (unsigned short*)d_ws;     // needs 2*8MB = 16MB of ws
  unsigned short* Vt = Kb + elems;

  const int n4 = (int)(elems / 4);                // 1,048,576 float4 groups
  convert_bf16<<<n4 / 256, 256, 0, stream>>>(k, Kb, n4);
  transpose_v_bf16<<<dim3(T_SEQ / 32, DH / 32, 16), dim3(32, 8), 0, stream>>>(v, Vt);
  attn_fwd<<<dim3(32, 16), 256, 0, stream>>>(q, Kb, Vt, out, maskp);
}